// Round 10
// baseline (234.605 us; speedup 1.0000x reference)
//
#include <hip/hip_runtime.h>
#include <hip/hip_fp16.h>

#define BB 4
#define NN 8192
#define DD 256
#define HH 8
#define MM 32768   // BB*NN

typedef __attribute__((ext_vector_type(8))) _Float16 half8;
typedef __attribute__((ext_vector_type(4))) _Float16 half4;
typedef __attribute__((ext_vector_type(4))) float f32x4;

#define GLL(src, dst)                                                        \
  __builtin_amdgcn_global_load_lds(                                          \
      (const __attribute__((address_space(1))) void*)(src),                  \
      (__attribute__((address_space(3))) void*)(dst), 16, 0, 0)

// ---------------- K0: W -> fragment-ordered fp16 ----------------
// wf[((h*4+kt)*2+sp)*12 + cf][lane l][e] = W_qkv[kt*64+sp*32+(l>>4)*8+e]
//                                               [ (cf>>2)*512 + h*64 + (cf&3)*16 + (l&15) ]
// Each wave B-fragment load becomes ONE contiguous 1 KB global_load_dwordx4.
__global__ void __launch_bounds__(256) k_cvt_w(const float* __restrict__ w,
                                               _Float16* __restrict__ wf) {
  int idx = blockIdx.x * 256 + threadIdx.x;   // 0..393215
  int e = idx & 7;
  int l = (idx >> 3) & 63;
  int chunk = idx >> 9;
  int cf = chunk % 12;
  int rem = chunk / 12;
  int sp = rem & 1;
  int p = rem >> 1;                            // h*4 + kt
  int hh = p >> 2, kt = p & 3;
  int lr = l & 15, lg = l >> 4;
  int gc = (cf >> 2) * 512 + hh * 64 + (cf & 3) * 16 + lr;
  int kidx = kt * 64 + sp * 32 + lg * 8 + e;
  wf[idx] = (_Float16)w[(size_t)kidx * 1536 + gc];
}

// ---------------- K1: qkv GEMM + norm + rotary + fused dots-partial ----------------
// grid(1024): rowtile = bid>>1 (64 rows), h0 = (bid&1)*4 (4 heads). 4 waves = (rh,ch):
// rows rh*32..+31 (2 row-frags). ch=0 -> k[0..63]+q[0..31] (x-rot); ch=1 -> v+q_hi (y-rot).
// B-fragments loaded DIRECTLY from global (fragment-ordered wf, L2-resident):
// the GEMM main loop has NO barriers and NO LDS. LDS = kv dots scratch only (22.5 KB).
__global__ void __launch_bounds__(256) k_qkv(const float* __restrict__ x,
                                             const _Float16* __restrict__ wf,
                                             const float* __restrict__ pos,
                                             _Float16* __restrict__ q16,
                                             _Float16* __restrict__ part16) {
  __shared__ alignas(16) _Float16 kv[11264];   // kT [64 d][88 r]; vT at +5632
  const int bid = blockIdx.x;
  const int rowtile = bid >> 1;
  const int row0 = rowtile * 64;
  const int h0 = (bid & 1) * 4;
  const int t = threadIdx.x;
  const int wv = t >> 6, l = t & 63, lr = l & 15, lg = l >> 4;
  const int rh = wv >> 1, ch = wv & 1;
  const int rowA = row0 + rh * 32 + lr;        // rs=0 row; rs=1 is +16

  const int cm0 = ch ? 8 : 4;                  // section frag base (k or v)
  const int cm4 = ch ? 2 : 0;                  // q frag base

  // ---- x fragments for both row-frags: coalesced fp32 loads -> fp16 regs ----
  half8 afr[2][8];
#pragma unroll
  for (int rs = 0; rs < 2; ++rs)
#pragma unroll
    for (int c = 0; c < 8; ++c) {    // c = kt*2 + sp
      const float* src = x + (size_t)(rowA + rs * 16) * 256 + c * 32 + lg * 8;
      float4 a = *(const float4*)src;
      float4 b = *(const float4*)(src + 4);
      half8 hv;
      hv[0] = (_Float16)a.x; hv[1] = (_Float16)a.y; hv[2] = (_Float16)a.z; hv[3] = (_Float16)a.w;
      hv[4] = (_Float16)b.x; hv[5] = (_Float16)b.y; hv[6] = (_Float16)b.z; hv[7] = (_Float16)b.w;
      afr[rs][c] = hv;
    }

  // ---- rotary angles: both dims, freq index = lg*4+j ----
  float sx[2][4], cx[2][4], sy[2][4], cy[2][4];
#pragma unroll
  for (int rs = 0; rs < 2; ++rs) {
    float px = pos[(size_t)(rowA + rs * 16) * 2 + 0] * 64.0f;
    float py = pos[(size_t)(rowA + rs * 16) * 2 + 1] * 64.0f;
#pragma unroll
    for (int j = 0; j < 4; ++j) {
      float invf = exp2f((float)(lg * 4 + j) * -0.8304820237218405f);  // 10000^(-fi/16)
      __sincosf(px * invf, &sx[rs][j], &cx[rs][j]);
      __sincosf(py * invf, &sy[rs][j], &cy[rs][j]);
    }
  }

#pragma unroll 1
  for (int h = 0; h < 4; ++h) {
    const int habs = h0 + h;
    f32x4 acc[6][2] = {};   // [frag u: 0-3 section, 4-5 q][row-frag rs]
#pragma unroll
    for (int kt = 0; kt < 4; ++kt) {
#pragma unroll
      for (int sp = 0; sp < 2; ++sp) {
        const _Float16* wp =
            wf + ((size_t)(((habs * 4 + kt) * 2 + sp) * 12) << 9) + l * 8;
        half8 bf[6];
#pragma unroll
        for (int u = 0; u < 4; ++u) bf[u] = *(const half8*)(wp + ((cm0 + u) << 9));
#pragma unroll
        for (int u = 0; u < 2; ++u) bf[4 + u] = *(const half8*)(wp + ((cm4 + u) << 9));
#pragma unroll
        for (int u = 0; u < 6; ++u)
#pragma unroll
          for (int rs = 0; rs < 2; ++rs)
            acc[u][rs] = __builtin_amdgcn_mfma_f32_16x16x32_f16(
                bf[u], afr[rs][kt * 2 + sp], acc[u][rs], 0, 0, 0);
      }
    }

    // ---- section norm stats (ch=0: k, ch=1: v) — fully in-wave ----
    float sm[2] = {0.f, 0.f}, s2[2] = {0.f, 0.f};
#pragma unroll
    for (int rs = 0; rs < 2; ++rs) {
#pragma unroll
      for (int u = 0; u < 4; ++u)
#pragma unroll
        for (int j = 0; j < 4; ++j) {
          float v = acc[u][rs][j];
          sm[rs] += v; s2[rs] += v * v;
        }
      sm[rs] += __shfl_xor(sm[rs], 16, 64);  sm[rs] += __shfl_xor(sm[rs], 32, 64);
      s2[rs] += __shfl_xor(s2[rs], 16, 64);  s2[rs] += __shfl_xor(s2[rs], 32, 64);
    }
    float mn[2], inv[2];
#pragma unroll
    for (int rs = 0; rs < 2; ++rs) {
      mn[rs] = sm[rs] * 0.015625f;
      inv[rs] = rsqrtf(s2[rs] * 0.015625f - mn[rs] * mn[rs] + 1e-5f);
    }

    if (ch == 0) {
      // ---- k: norm + rotary -> kv kT[d][r]; q_lo: x-rotary -> global ----
#pragma unroll
      for (int rs = 0; rs < 2; ++rs) {
        int r = rh * 32 + rs * 16 + lr;
        half4 o0, o1;
#pragma unroll
        for (int j = 0; j < 4; ++j) {
          float k0 = (acc[0][rs][j] - mn[rs]) * inv[rs];
          float k1 = (acc[1][rs][j] - mn[rs]) * inv[rs];
          float k2 = (acc[2][rs][j] - mn[rs]) * inv[rs];
          float k3 = (acc[3][rs][j] - mn[rs]) * inv[rs];
          int d0 = lg * 4 + j;
          kv[d0 * 88 + r]        = (_Float16)(k0 * cx[rs][j] - k1 * sx[rs][j]);
          kv[(d0 + 16) * 88 + r] = (_Float16)(k1 * cx[rs][j] + k0 * sx[rs][j]);
          kv[(d0 + 32) * 88 + r] = (_Float16)(k2 * cy[rs][j] - k3 * sy[rs][j]);
          kv[(d0 + 48) * 88 + r] = (_Float16)(k3 * cy[rs][j] + k2 * sy[rs][j]);
          float a0 = acc[4][rs][j], a1 = acc[5][rs][j];
          o0[j] = (_Float16)(a0 * cx[rs][j] - a1 * sx[rs][j]);
          o1[j] = (_Float16)(a1 * cx[rs][j] + a0 * sx[rs][j]);
        }
        size_t qb = (size_t)(rowA + rs * 16) * 512 + habs * 64 + lg * 4;
        *(half4*)(q16 + qb) = o0;
        *(half4*)(q16 + qb + 16) = o1;
      }
    } else {
      // ---- v: norm -> kv vT[e][r]; q_hi: y-rotary -> global ----
#pragma unroll
      for (int rs = 0; rs < 2; ++rs) {
        int r = rh * 32 + rs * 16 + lr;
        half4 o0, o1;
#pragma unroll
        for (int j = 0; j < 4; ++j) {
          int d0 = lg * 4 + j;
          kv[5632 + d0 * 88 + r]        = (_Float16)((acc[0][rs][j] - mn[rs]) * inv[rs]);
          kv[5632 + (d0 + 16) * 88 + r] = (_Float16)((acc[1][rs][j] - mn[rs]) * inv[rs]);
          kv[5632 + (d0 + 32) * 88 + r] = (_Float16)((acc[2][rs][j] - mn[rs]) * inv[rs]);
          kv[5632 + (d0 + 48) * 88 + r] = (_Float16)((acc[3][rs][j] - mn[rs]) * inv[rs]);
          float a0 = acc[4][rs][j], a1 = acc[5][rs][j];
          o0[j] = (_Float16)(a0 * cy[rs][j] - a1 * sy[rs][j]);
          o1[j] = (_Float16)(a1 * cy[rs][j] + a0 * sy[rs][j]);
        }
        size_t qb = (size_t)(rowA + rs * 16) * 512 + habs * 64 + 32 + lg * 4;
        *(half4*)(q16 + qb) = o0;
        *(half4*)(q16 + qb + 16) = o1;
      }
    }
    asm volatile("s_waitcnt lgkmcnt(0)" ::: "memory");   // kv writes visible
    __builtin_amdgcn_s_barrier();

    // ---- dots partial: D[d][e] = sum_rows kT[d][row] vT[e][row], K=64 ----
    f32x4 dacc[4] = {};
#pragma unroll
    for (int ks = 0; ks < 2; ++ks) {
      half8 adf = *(const half8*)(kv + (wv * 16 + lr) * 88 + ks * 32 + lg * 8);
#pragma unroll
      for (int ep = 0; ep < 4; ++ep) {
        half8 bdf = *(const half8*)(kv + 5632 + (ep * 16 + lr) * 88 + ks * 32 + lg * 8);
        dacc[ep] = __builtin_amdgcn_mfma_f32_16x16x32_f16(adf, bdf, dacc[ep], 0, 0, 0);
      }
    }
    asm volatile("s_waitcnt lgkmcnt(0)" ::: "memory");   // dots reads done
    __builtin_amdgcn_s_barrier();                        // before next head overwrites kv

    // partial layout [e][d]: lane holds d = wv*16 + lg*4+{0..3}, e = ep*16+lr
    _Float16* pdst = part16 + ((size_t)rowtile * 8 + habs) * 4096;
#pragma unroll
    for (int ep = 0; ep < 4; ++ep) {
      half4 o;
#pragma unroll
      for (int j = 0; j < 4; ++j) o[j] = (_Float16)dacc[ep][j];
      *(half4*)(pdst + (ep * 16 + lr) * 64 + wv * 16 + lg * 4) = o;
    }
  }
}

// ---------------- K2: reduce 512 rowtile partials -> dots fp32 [32 bh][e*64+d] ----
__global__ void __launch_bounds__(256) k_pred(const _Float16* __restrict__ part16,
                                              float* __restrict__ dots) {
  __shared__ float red[4][512];
  const int bh = blockIdx.x >> 3, sl = blockIdx.x & 7;
  const int b = bh >> 3, h = bh & 7;
  const int t = threadIdx.x, wv = t >> 6, l = t & 63;
  float s[8] = {};
  const _Float16* base = part16 + ((size_t)(b * 128) * 8 + h) * 4096 + sl * 512 + l * 8;
#pragma unroll 4
  for (int i = 0; i < 32; ++i) {
    int rt = wv * 32 + i;
    half8 v = *(const half8*)(base + (size_t)rt * 32768);
#pragma unroll
    for (int m = 0; m < 8; ++m) s[m] += (float)v[m];
  }
#pragma unroll
  for (int m = 0; m < 8; ++m) red[wv][l * 8 + m] = s[m];
  __syncthreads();
#pragma unroll
  for (int e = t; e < 512; e += 256) {
    float r = red[0][e] + red[1][e] + red[2][e] + red[3][e];
    dots[(size_t)bh * 4096 + sl * 512 + e] = r;
  }
}

// ---------------- K2b: wdt[b][j][h*64+d] = (1/N) sum_e dotsT[e][d] wout[h*64+e][j]
// grid(32, 4): bid = b*8+h, j-quarter = blockIdx.y*64.
__global__ void __launch_bounds__(256) k_wd(const float* __restrict__ dots,
                                            const float* __restrict__ wout,
                                            _Float16* __restrict__ wdt) {
  __shared__ alignas(16) _Float16 a_lds[4096];    // [64 d][64 e] swizzled, 8 KB
  __shared__ alignas(16) _Float16 b_lds[4096];    // [64 jl][64 e] swizzled, 8 KB
  const int bid = blockIdx.x, b = bid >> 3, hh = bid & 7;
  const int j0 = blockIdx.y * 64;
  const int t = threadIdx.x, wv = t >> 6, l = t & 63, lr = l & 15, lg = l >> 4;

  // A: dots [e][d] fp32 -> a_lds [d][e] fp16 (scaled)
#pragma unroll
  for (int g = 0; g < 4; ++g) {
    int i4 = (g * 256 + t) * 4;  // 0..4095, e = i4>>6, d = i4&63
    f32x4 s = *(const f32x4*)(dots + (size_t)bid * 4096 + i4);
    int e = i4 >> 6, d0 = i4 & 63;
#pragma unroll
    for (int m = 0; m < 4; ++m) {
      int d = d0 + m;
      *(_Float16*)((char*)a_lds + d * 128 + ((e * 2) ^ ((d & 7) << 4))) =
          (_Float16)(s[m] * (1.0f / 8192.0f));
    }
  }
  // B: wout rows hh*64..+63, cols j0..+63, transposed to [jl][e] fp16
#pragma unroll
  for (int g = 0; g < 4; ++g) {
    int i4 = (g * 256 + t) * 4;  // 0..4095: e = i4>>6, jl = i4&63
    int e = i4 >> 6, jl0 = i4 & 63;
    f32x4 u = *(const f32x4*)(wout + (size_t)(hh * 64 + e) * 256 + j0 + jl0);
#pragma unroll
    for (int m = 0; m < 4; ++m) {
      int jl = jl0 + m;
      *(_Float16*)((char*)b_lds + jl * 128 + ((e * 2) ^ ((jl & 7) << 4))) = (_Float16)u[m];
    }
  }
  __syncthreads();

  f32x4 acc[4] = {};
#pragma unroll
  for (int sp = 0; sp < 2; ++sp) {
    int kb = sp * 64 + lg * 16;
    half8 bf;
    {
      int jl = wv * 16 + lr;
      bf = *(const half8*)((const char*)b_lds + jl * 128 + (kb ^ ((jl & 7) << 4)));
    }
#pragma unroll
    for (int ad = 0; ad < 4; ++ad) {
      int d = ad * 16 + lr;
      half8 af = *(const half8*)((const char*)a_lds + d * 128 + (kb ^ ((d & 7) << 4)));
      acc[ad] = __builtin_amdgcn_mfma_f32_16x16x32_f16(af, bf, acc[ad], 0, 0, 0);
    }
  }
  // D[row=d][col=j]: lane holds d = ad*16+lg*4+{0..3}, j = j0 + wv*16 + lr
#pragma unroll
  for (int ad = 0; ad < 4; ++ad) {
    int j = j0 + wv * 16 + lr;
    half4 o;
#pragma unroll
    for (int jj = 0; jj < 4; ++jj) o[jj] = (_Float16)acc[ad][jj];
    *(half4*)(wdt + (size_t)b * 131072 + (size_t)j * 512 + hh * 64 + ad * 16 + lg * 4) = o;
  }
}

// ---------------- K3: out = q16 @ wdt[b] + b_out ----------------
__global__ void __launch_bounds__(256) k_out(const _Float16* __restrict__ q16,
                                             const _Float16* __restrict__ wdt,
                                             const float* __restrict__ bout,
                                             float* __restrict__ out) {
  __shared__ alignas(16) _Float16 qa[2][4096];     // [64 rows][64 K] 8 KB x2
  __shared__ alignas(16) _Float16 wtile[2][16384]; // [256 cols][64 K] 32 KB x2
  const int row0 = blockIdx.x * 64;
  const int b = row0 >> 13;
  const _Float16* wb = wdt + (size_t)b * 131072;
  const int t = threadIdx.x, wv = t >> 6, l = t & 63, lr = l & 15, lg = l >> 4;

  auto stage = [&](int buf, int kt) {
#pragma unroll
    for (int call = 0; call < 2; ++call) {
      int ob = (call * 4 + wv) * 1024;
      int o = ob + l * 16;
      int r = o >> 7;
      int kb = (o & 127) ^ ((r & 7) << 4);
      const char* src = (const char*)(q16 + (size_t)(row0 + r) * 512 + kt * 64) + kb;
      GLL(src, (char*)&qa[buf][0] + ob);
    }
#pragma unroll
    for (int call = 0; call < 8; ++call) {
      int ob = (call * 4 + wv) * 1024;
      int o = ob + l * 16;
      int c = o >> 7;
      int kb = (o & 127) ^ ((c & 7) << 4);
      const char* src = (const char*)(wb + (size_t)c * 512 + kt * 64) + kb;
      GLL(src, (char*)&wtile[buf][0] + ob);
    }
  };

  f32x4 acc[16] = {};
  stage(0, 0);
  __syncthreads();
#pragma unroll 1
  for (int kt = 0; kt < 8; ++kt) {
    int cur = kt & 1;
    if (kt < 7) stage(cur ^ 1, kt + 1);
    const int arow = wv * 16 + lr;
#pragma unroll
    for (int sp = 0; sp < 2; ++sp) {
      int kb = sp * 64 + lg * 16;
      half8 af = *(const half8*)((const char*)&qa[cur][0] + arow * 128 + (kb ^ ((arow & 7) << 4)));
#pragma unroll
      for (int cf = 0; cf < 16; ++cf) {
        int c = cf * 16 + lr;
        half8 bf = *(const half8*)((const char*)&wtile[cur][0] + c * 128 + (kb ^ ((c & 7) << 4)));
        acc[cf] = __builtin_amdgcn_mfma_f32_16x16x32_f16(af, bf, acc[cf], 0, 0, 0);
      }
    }
    __syncthreads();
  }
#pragma unroll
  for (int cf = 0; cf < 16; ++cf) {
    int col = cf * 16 + lr;
    float bo = bout[col];
#pragma unroll
    for (int j = 0; j < 4; ++j) {
      int grow = row0 + wv * 16 + lg * 4 + j;
      out[(size_t)grow * 256 + col] = acc[cf][j] + bo;
    }
  }
}

// ---------------- launch ----------------
extern "C" void kernel_launch(void* const* d_in, const int* in_sizes, int n_in,
                              void* d_out, int out_size, void* d_ws, size_t ws_size,
                              hipStream_t stream) {
  const float* x    = (const float*)d_in[0];
  const float* pos  = (const float*)d_in[1];
  const float* wqkv = (const float*)d_in[2];
  const float* wout = (const float*)d_in[3];
  const float* bout = (const float*)d_in[4];
  float* out = (float*)d_out;
  char* ws = (char*)d_ws;

  _Float16* wf16   = (_Float16*)(ws + 0);          //    786,432 B (fragment-ordered)
  _Float16* q16    = (_Float16*)(ws + 786432);     // 33,554,432 B
  _Float16* part16 = (_Float16*)(ws + 34340864);   // 33,554,432 B
  float*    dots   = (float*)   (ws + 67895296);   //    524,288 B
  _Float16* wdt    = (_Float16*)(ws + 68419584);   //  1,048,576 B (end 69,468,160)

  k_cvt_w<<<1536, 256, 0, stream>>>(wqkv, wf16);
  k_qkv<<<1024, 256, 0, stream>>>(x, wf16, pos, q16, part16);
  k_pred<<<256, 256, 0, stream>>>(part16, dots);
  k_wd<<<dim3(32, 4), 256, 0, stream>>>(dots, wout, wdt);
  k_out<<<512, 256, 0, stream>>>(q16, wdt, bout, out);
}

// Round 11
// 112.348 us; speedup vs baseline: 2.0882x; 2.0882x over previous
//
#include <hip/hip_runtime.h>
#include <hip/hip_fp16.h>

#define BB 4
#define NN 8192
#define DD 256
#define HH 8
#define MM 32768   // BB*NN

typedef __attribute__((ext_vector_type(8))) _Float16 half8;
typedef __attribute__((ext_vector_type(4))) _Float16 half4;
typedef __attribute__((ext_vector_type(4))) float f32x4;
typedef __attribute__((ext_vector_type(16))) float f32x16;

#define GLL(src, dst)                                                        \
  __builtin_amdgcn_global_load_lds(                                          \
      (const __attribute__((address_space(1))) void*)(src),                  \
      (__attribute__((address_space(3))) void*)(dst), 16, 0, 0)

// ---------------- K0: W conversion ----------------
// W_qkv [256][1536] fp32 -> Wt [1536][256] fp16 (transposed)
__global__ void __launch_bounds__(256) k_cvt_w(const float* __restrict__ w,
                                               _Float16* __restrict__ wt) {
  int idx = blockIdx.x * 256 + threadIdx.x;  // 0..393215
  int k = idx / 1536, c = idx % 1536;
  wt[(size_t)c * 256 + k] = (_Float16)w[idx];
}

// ---------------- K1: qkv GEMM (32x32 MFMA) + norm + rotary + fused dots ----------------
// grid(512): 64 rows, 8 heads, K=256 in 4 panels of 64. 4 waves = (rh, ch):
// rows rh*32..+31 (xrow = lane&31). Tiles of 32 cols: q={t0,t1} k={t2,t3} v={t4,t5};
// ch=0 -> {k0,k1,q_lo}, ch=1 -> {v0,v1,q_hi}. 12 b128 reads feed 12 32x32-MFMA/phase.
// C/D map: xrow=lane&31, wcol=(reg&3)+8*(reg>>2)+4*(lane>>5).
// W staged via 3-buffer ring, counted vmcnt(6); epilogue barriers lgkm-only.
__global__ void __launch_bounds__(256) k_qkv(const float* __restrict__ x,
                                             const _Float16* __restrict__ wt,
                                             const float* __restrict__ pos,
                                             _Float16* __restrict__ q16,
                                             _Float16* __restrict__ part16) {
  __shared__ alignas(16) _Float16 rbuf[3][12288];  // 3 x [192 cols][64 K] swizzled, 72 KB
  const int row0 = blockIdx.x * 64;
  const int t = threadIdx.x;
  const int wv = t >> 6, l = t & 63, lr = l & 15, lg = l >> 4;
  const int rh = wv >> 1, ch = wv & 1;
  const int hi = l >> 5;
  const int xr = l & 31;
  const int row = rh * 32 + xr;                 // block-local row 0..63
  const int growN = row0 + row;

  // ---- x fragments: 16 K-steps of 16, lane holds row (l&31), k (l>>5)*8 ----
  half8 afr[16];
#pragma unroll
  for (int st = 0; st < 16; ++st) {
    const float* src = x + (size_t)growN * 256 + st * 16 + hi * 8;
    float4 a = *(const float4*)src;
    float4 b = *(const float4*)(src + 4);
    half8 hv;
    hv[0] = (_Float16)a.x; hv[1] = (_Float16)a.y; hv[2] = (_Float16)a.z; hv[3] = (_Float16)a.w;
    hv[4] = (_Float16)b.x; hv[5] = (_Float16)b.y; hv[6] = (_Float16)b.z; hv[7] = (_Float16)b.w;
    afr[st] = hv;
  }

  // ---- rotary angles: fi(r8) = (r8&3)+8*(r8>>2)+4*hi, one row per lane ----
  const float px = pos[(size_t)growN * 2 + 0] * 64.0f;
  const float py = pos[(size_t)growN * 2 + 1] * 64.0f;
  float sxA[8], cxA[8], syA[8], cyA[8];
#pragma unroll
  for (int r8 = 0; r8 < 8; ++r8) {
    float fi = (float)((r8 & 3) + 8 * (r8 >> 2) + 4 * hi);
    float invf = exp2f(fi * -0.8304820237218405f);  // 10000^(-fi/16)
    __sincosf(px * invf, &sxA[r8], &cxA[r8]);
    __sincosf(py * invf, &syA[r8], &cyA[r8]);
  }

  // tile id list for this wave: {section0, section1, q-tile}
  const int tl0 = ch ? 4 : 2, tl1 = ch ? 5 : 3, tlq = ch;

  // ---- W stage for phase p (p = h*4 + kt); data index wraps past 31 ----
  auto stageP = [&](int p) {
    const int pd = p & 31;
    const int hh = pd >> 2, kt = pd & 3;
    char* dst = (char*)&rbuf[p % 3][0];
#pragma unroll
    for (int call = 0; call < 6; ++call) {
      int ob = (call * 4 + wv) * 1024;             // wave-uniform dest base (bytes)
      int o = ob + l * 16;                         // this lane's dest byte
      int c = o >> 7;                              // col 0..191
      int kb = (o & 127) ^ ((c & 7) << 4);         // logical K byte (XOR swizzle)
      int gc = ((c >> 6) << 9) + (hh << 6) + (c & 63);  // global wt row
      const char* src = (const char*)(wt + (size_t)gc * 256 + kt * 64) + kb;
      GLL(src, dst + ob);
    }
  };

  stageP(0); stageP(1);
  asm volatile("s_waitcnt vmcnt(6)" ::: "memory");   // stage(0) complete
  __builtin_amdgcn_s_barrier();

#pragma unroll 1
  for (int h = 0; h < 8; ++h) {
    f32x16 acc[3] = {};   // [tile: sec0, sec1, q]
#pragma unroll
    for (int kt = 0; kt < 4; ++kt) {               // unrolled: afr static index
      const int p = h * 4 + kt;
      stageP(p + 2);                               // 6 GLL, lands 2 phases ahead
      const char* wbp = (const char*)&rbuf[p % 3][0];
#pragma unroll
      for (int ks = 0; ks < 4; ++ks) {             // K-steps of 16 within panel
        const int kb = ks * 32 + hi * 16;          // byte offset in 128B K-row
        half8 af = afr[kt * 4 + ks];
        {
          int c = tl0 * 32 + xr;
          half8 bf = *(const half8*)(wbp + c * 128 + (kb ^ ((c & 7) << 4)));
          acc[0] = __builtin_amdgcn_mfma_f32_32x32x16_f16(bf, af, acc[0], 0, 0, 0);
        }
        {
          int c = tl1 * 32 + xr;
          half8 bf = *(const half8*)(wbp + c * 128 + (kb ^ ((c & 7) << 4)));
          acc[1] = __builtin_amdgcn_mfma_f32_32x32x16_f16(bf, af, acc[1], 0, 0, 0);
        }
        {
          int c = tlq * 32 + xr;
          half8 bf = *(const half8*)(wbp + c * 128 + (kb ^ ((c & 7) << 4)));
          acc[2] = __builtin_amdgcn_mfma_f32_32x32x16_f16(bf, af, acc[2], 0, 0, 0);
        }
      }
      asm volatile("s_waitcnt vmcnt(6)" ::: "memory");  // counted: newest stage in flight
      __builtin_amdgcn_s_barrier();
    }
    // (4h+3)%3 == h%3: just-read buffer dead until stage(4h+6)
    _Float16* dead = &rbuf[h % 3][0];   // kT [64 d][88 r]; vT at +5632

    // ---- section norm stats — one shfl_xor(32) ----
    float sm = 0.f, s2 = 0.f;
#pragma unroll
    for (int u = 0; u < 2; ++u)
#pragma unroll
      for (int r = 0; r < 16; ++r) {
        float v = acc[u][r];
        sm += v; s2 += v * v;
      }
    sm += __shfl_xor(sm, 32, 64);
    s2 += __shfl_xor(s2, 32, 64);
    const float mn = sm * 0.015625f;
    const float inv = rsqrtf(s2 * 0.015625f - mn * mn + 1e-5f);

    half4 oqa[2], oqb[2];
    if (ch == 0) {
      // k: norm + 2D rotary -> dead kT[d][row]; q_lo: x-rotary
#pragma unroll
      for (int r8 = 0; r8 < 8; ++r8) {
        int d = (r8 & 3) + 8 * (r8 >> 2) + 4 * hi;       // pair base 0..15
        float k0 = (acc[0][r8] - mn) * inv,  k1 = (acc[0][r8 + 8] - mn) * inv;
        float k2 = (acc[1][r8] - mn) * inv,  k3 = (acc[1][r8 + 8] - mn) * inv;
        dead[d * 88 + row]        = (_Float16)(k0 * cxA[r8] - k1 * sxA[r8]);
        dead[(d + 16) * 88 + row] = (_Float16)(k1 * cxA[r8] + k0 * sxA[r8]);
        dead[(d + 32) * 88 + row] = (_Float16)(k2 * cyA[r8] - k3 * syA[r8]);
        dead[(d + 48) * 88 + row] = (_Float16)(k3 * cyA[r8] + k2 * syA[r8]);
        float a0 = acc[2][r8], a1 = acc[2][r8 + 8];
        oqa[r8 >> 2][r8 & 3] = (_Float16)(a0 * cxA[r8] - a1 * sxA[r8]);
        oqb[r8 >> 2][r8 & 3] = (_Float16)(a1 * cxA[r8] + a0 * sxA[r8]);
      }
    } else {
      // v: norm -> dead vT[e][row]; q_hi: y-rotary
#pragma unroll
      for (int r = 0; r < 16; ++r) {
        int d = (r & 3) + 8 * (r >> 2) + 4 * hi;         // 0..31
        dead[5632 + d * 88 + row]        = (_Float16)((acc[0][r] - mn) * inv);
        dead[5632 + (d + 32) * 88 + row] = (_Float16)((acc[1][r] - mn) * inv);
      }
#pragma unroll
      for (int r8 = 0; r8 < 8; ++r8) {
        float a0 = acc[2][r8], a1 = acc[2][r8 + 8];
        oqa[r8 >> 2][r8 & 3] = (_Float16)(a0 * cyA[r8] - a1 * syA[r8]);
        oqb[r8 >> 2][r8 & 3] = (_Float16)(a1 * cyA[r8] + a0 * syA[r8]);
      }
    }
    // q stores: dims base = ch*32 + {4hi, 8+4hi} and +16
    {
      size_t qb = (size_t)growN * 512 + h * 64 + ch * 32 + 4 * hi;
      *(half4*)(q16 + qb)      = oqa[0];
      *(half4*)(q16 + qb + 8)  = oqa[1];
      *(half4*)(q16 + qb + 16) = oqb[0];
      *(half4*)(q16 + qb + 24) = oqb[1];
    }
    asm volatile("s_waitcnt lgkmcnt(0)" ::: "memory");   // kv writes visible (no vm drain)
    __builtin_amdgcn_s_barrier();

    // ---- dots partial: D[d][e] = sum_rows kT[d][row] vT[e][row], K=64 ----
    f32x4 dacc[4] = {};
#pragma unroll
    for (int ks = 0; ks < 2; ++ks) {
      half8 adf = *(const half8*)(dead + (wv * 16 + lr) * 88 + ks * 32 + lg * 8);
#pragma unroll
      for (int ep = 0; ep < 4; ++ep) {
        half8 bdf = *(const half8*)(dead + 5632 + (ep * 16 + lr) * 88 + ks * 32 + lg * 8);
        dacc[ep] = __builtin_amdgcn_mfma_f32_16x16x32_f16(adf, bdf, dacc[ep], 0, 0, 0);
      }
    }
    asm volatile("s_waitcnt lgkmcnt(0)" ::: "memory");   // dots reads done
    __builtin_amdgcn_s_barrier();                        // before next stage overwrites

    // partial layout [e][d]: lane holds d = wv*16 + lg*4+{0..3}, e = ep*16+lr
    _Float16* pdst = part16 + ((size_t)blockIdx.x * 8 + h) * 4096;
#pragma unroll
    for (int ep = 0; ep < 4; ++ep) {
      half4 o;
#pragma unroll
      for (int j = 0; j < 4; ++j) o[j] = (_Float16)dacc[ep][j];
      *(half4*)(pdst + (ep * 16 + lr) * 64 + wv * 16 + lg * 4) = o;
    }
  }
}

// ---------------- K2: reduce 512 rowtile partials -> dots fp32 [32 bh][e*64+d] ----
__global__ void __launch_bounds__(256) k_pred(const _Float16* __restrict__ part16,
                                              float* __restrict__ dots) {
  __shared__ float red[4][512];
  const int bh = blockIdx.x >> 3, sl = blockIdx.x & 7;
  const int b = bh >> 3, h = bh & 7;
  const int t = threadIdx.x, wv = t >> 6, l = t & 63;
  float s[8] = {};
  const _Float16* base = part16 + ((size_t)(b * 128) * 8 + h) * 4096 + sl * 512 + l * 8;
#pragma unroll 4
  for (int i = 0; i < 32; ++i) {
    int rt = wv * 32 + i;
    half8 v = *(const half8*)(base + (size_t)rt * 32768);
#pragma unroll
    for (int m = 0; m < 8; ++m) s[m] += (float)v[m];
  }
#pragma unroll
  for (int m = 0; m < 8; ++m) red[wv][l * 8 + m] = s[m];
  __syncthreads();
#pragma unroll
  for (int e = t; e < 512; e += 256) {
    float r = red[0][e] + red[1][e] + red[2][e] + red[3][e];
    dots[(size_t)bh * 4096 + sl * 512 + e] = r;
  }
}

// ---------------- K2b: wdt[b][j][h*64+d] = (1/N) sum_e dotsT[e][d] wout[h*64+e][j]
// grid(32, 4): bid = b*8+h, j-quarter = blockIdx.y*64.
__global__ void __launch_bounds__(256) k_wd(const float* __restrict__ dots,
                                            const float* __restrict__ wout,
                                            _Float16* __restrict__ wdt) {
  __shared__ alignas(16) _Float16 a_lds[4096];    // [64 d][64 e] swizzled, 8 KB
  __shared__ alignas(16) _Float16 b_lds[4096];    // [64 jl][64 e] swizzled, 8 KB
  const int bid = blockIdx.x, b = bid >> 3, hh = bid & 7;
  const int j0 = blockIdx.y * 64;
  const int t = threadIdx.x, wv = t >> 6, l = t & 63, lr = l & 15, lg = l >> 4;

  // A: dots [e][d] fp32 -> a_lds [d][e] fp16 (scaled)
#pragma unroll
  for (int g = 0; g < 4; ++g) {
    int i4 = (g * 256 + t) * 4;  // 0..4095, e = i4>>6, d = i4&63
    f32x4 s = *(const f32x4*)(dots + (size_t)bid * 4096 + i4);
    int e = i4 >> 6, d0 = i4 & 63;
#pragma unroll
    for (int m = 0; m < 4; ++m) {
      int d = d0 + m;
      *(_Float16*)((char*)a_lds + d * 128 + ((e * 2) ^ ((d & 7) << 4))) =
          (_Float16)(s[m] * (1.0f / 8192.0f));
    }
  }
  // B: wout rows hh*64..+63, cols j0..+63, transposed to [jl][e] fp16
#pragma unroll
  for (int g = 0; g < 4; ++g) {
    int i4 = (g * 256 + t) * 4;  // 0..4095: e = i4>>6, jl = i4&63
    int e = i4 >> 6, jl0 = i4 & 63;
    f32x4 u = *(const f32x4*)(wout + (size_t)(hh * 64 + e) * 256 + j0 + jl0);
#pragma unroll
    for (int m = 0; m < 4; ++m) {
      int jl = jl0 + m;
      *(_Float16*)((char*)b_lds + jl * 128 + ((e * 2) ^ ((jl & 7) << 4))) = (_Float16)u[m];
    }
  }
  __syncthreads();

  f32x4 acc[4] = {};
#pragma unroll
  for (int sp = 0; sp < 2; ++sp) {
    int kb = sp * 64 + lg * 16;
    half8 bf;
    {
      int jl = wv * 16 + lr;
      bf = *(const half8*)((const char*)b_lds + jl * 128 + (kb ^ ((jl & 7) << 4)));
    }
#pragma unroll
    for (int ad = 0; ad < 4; ++ad) {
      int d = ad * 16 + lr;
      half8 af = *(const half8*)((const char*)a_lds + d * 128 + (kb ^ ((d & 7) << 4)));
      acc[ad] = __builtin_amdgcn_mfma_f32_16x16x32_f16(af, bf, acc[ad], 0, 0, 0);
    }
  }
  // D[row=d][col=j]: lane holds d = ad*16+lg*4+{0..3}, j = j0 + wv*16 + lr
#pragma unroll
  for (int ad = 0; ad < 4; ++ad) {
    int j = j0 + wv * 16 + lr;
    half4 o;
#pragma unroll
    for (int jj = 0; jj < 4; ++jj) o[jj] = (_Float16)acc[ad][jj];
    *(half4*)(wdt + (size_t)b * 131072 + (size_t)j * 512 + hh * 64 + ad * 16 + lg * 4) = o;
  }
}

// ---------------- K3: out = q16 @ wdt[b] + b_out ----------------
__global__ void __launch_bounds__(256) k_out(const _Float16* __restrict__ q16,
                                             const _Float16* __restrict__ wdt,
                                             const float* __restrict__ bout,
                                             float* __restrict__ out) {
  __shared__ alignas(16) _Float16 qa[2][4096];     // [64 rows][64 K] 8 KB x2
  __shared__ alignas(16) _Float16 wtile[2][16384]; // [256 cols][64 K] 32 KB x2
  const int row0 = blockIdx.x * 64;
  const int b = row0 >> 13;
  const _Float16* wb = wdt + (size_t)b * 131072;
  const int t = threadIdx.x, wv = t >> 6, l = t & 63, lr = l & 15, lg = l >> 4;

  auto stage = [&](int buf, int kt) {
#pragma unroll
    for (int call = 0; call < 2; ++call) {
      int ob = (call * 4 + wv) * 1024;
      int o = ob + l * 16;
      int r = o >> 7;
      int kb = (o & 127) ^ ((r & 7) << 4);
      const char* src = (const char*)(q16 + (size_t)(row0 + r) * 512 + kt * 64) + kb;
      GLL(src, (char*)&qa[buf][0] + ob);
    }
#pragma unroll
    for (int call = 0; call < 8; ++call) {
      int ob = (call * 4 + wv) * 1024;
      int o = ob + l * 16;
      int c = o >> 7;
      int kb = (o & 127) ^ ((c & 7) << 4);
      const char* src = (const char*)(wb + (size_t)c * 512 + kt * 64) + kb;
      GLL(src, (char*)&wtile[buf][0] + ob);
    }
  };

  f32x4 acc[16] = {};
  stage(0, 0);
  __syncthreads();
#pragma unroll 1
  for (int kt = 0; kt < 8; ++kt) {
    int cur = kt & 1;
    if (kt < 7) stage(cur ^ 1, kt + 1);
    const int arow = wv * 16 + lr;
#pragma unroll
    for (int sp = 0; sp < 2; ++sp) {
      int kb = sp * 64 + lg * 16;
      half8 af = *(const half8*)((const char*)&qa[cur][0] + arow * 128 + (kb ^ ((arow & 7) << 4)));
#pragma unroll
      for (int cf = 0; cf < 16; ++cf) {
        int c = cf * 16 + lr;
        half8 bf = *(const half8*)((const char*)&wtile[cur][0] + c * 128 + (kb ^ ((c & 7) << 4)));
        acc[cf] = __builtin_amdgcn_mfma_f32_16x16x32_f16(af, bf, acc[cf], 0, 0, 0);
      }
    }
    __syncthreads();
  }
#pragma unroll
  for (int cf = 0; cf < 16; ++cf) {
    int col = cf * 16 + lr;
    float bo = bout[col];
#pragma unroll
    for (int j = 0; j < 4; ++j) {
      int grow = row0 + wv * 16 + lg * 4 + j;
      out[(size_t)grow * 256 + col] = acc[cf][j] + bo;
    }
  }
}

// ---------------- launch ----------------
extern "C" void kernel_launch(void* const* d_in, const int* in_sizes, int n_in,
                              void* d_out, int out_size, void* d_ws, size_t ws_size,
                              hipStream_t stream) {
  const float* x    = (const float*)d_in[0];
  const float* pos  = (const float*)d_in[1];
  const float* wqkv = (const float*)d_in[2];
  const float* wout = (const float*)d_in[3];
  const float* bout = (const float*)d_in[4];
  float* out = (float*)d_out;
  char* ws = (char*)d_ws;

  _Float16* wt16   = (_Float16*)(ws + 0);          //    786,432 B
  _Float16* q16    = (_Float16*)(ws + 786432);     // 33,554,432 B
  _Float16* part16 = (_Float16*)(ws + 34340864);   // 33,554,432 B
  float*    dots   = (float*)   (ws + 67895296);   //    524,288 B
  _Float16* wdt    = (_Float16*)(ws + 68419584);   //  1,048,576 B (end 69,468,160)

  k_cvt_w<<<1536, 256, 0, stream>>>(wqkv, wt16);
  k_qkv<<<512, 256, 0, stream>>>(x, wt16, pos, q16, part16);
  k_pred<<<256, 256, 0, stream>>>(part16, dots);
  k_wd<<<dim3(32, 4), 256, 0, stream>>>(dots, wout, wdt);
  k_out<<<512, 256, 0, stream>>>(q16, wdt, bout, out);
}

// Round 13
// 102.192 us; speedup vs baseline: 2.2957x; 1.0994x over previous
//
#include <hip/hip_runtime.h>
#include <hip/hip_fp16.h>

#define BB 4
#define NN 8192
#define DD 256
#define HH 8
#define MM 32768   // BB*NN

typedef __attribute__((ext_vector_type(8))) _Float16 half8;
typedef __attribute__((ext_vector_type(4))) _Float16 half4;
typedef __attribute__((ext_vector_type(4))) float f32x4;

#define GLL(src, dst)                                                        \
  __builtin_amdgcn_global_load_lds(                                          \
      (const __attribute__((address_space(1))) void*)(src),                  \
      (__attribute__((address_space(3))) void*)(dst), 16, 0, 0)

// ---------------- K0: W conversion ----------------
// W_qkv [256][1536] fp32 -> Wt [1536][256] fp16 (transposed)
__global__ void __launch_bounds__(256) k_cvt_w(const float* __restrict__ w,
                                               _Float16* __restrict__ wt) {
  int idx = blockIdx.x * 256 + threadIdx.x;  // 0..393215
  int k = idx / 1536, c = idx % 1536;
  wt[(size_t)c * 256 + k] = (_Float16)w[idx];
}

// ---------------- K1: qkv GEMM + norm + rotary + fused dots-partial ----------------
// grid(512): 64 rows, ALL 8 heads, K=256 in 4 panels of 64. 4 waves.
// x-frags in registers. W staged through a 3-buffer ring (24 KB each) with
// counted vmcnt(6) + raw barrier (T4): stages span phases, no drain-to-0.
// Dots scratch = the just-read (dead) ring buffer at each head boundary.
// [R7-exact: best verified k_qkv]
__global__ void __launch_bounds__(256) k_qkv(const float* __restrict__ x,
                                             const _Float16* __restrict__ wt,
                                             const float* __restrict__ pos,
                                             _Float16* __restrict__ q16,
                                             _Float16* __restrict__ part16) {
  __shared__ alignas(16) _Float16 rbuf[3][12288];  // 3 x [192 cols][64 K] swizzled, 72 KB
  const int row0 = blockIdx.x * 64;
  const int t = threadIdx.x;
  const int wv = t >> 6, l = t & 63, lr = l & 15, lg = l >> 4;
  const int myrow = row0 + wv * 16 + lr;

  // ---- x fragments: coalesced global loads, fp32 -> fp16, registers ----
  half8 afr[8];
#pragma unroll
  for (int c = 0; c < 8; ++c) {      // c = kt*2 + sp
    const float* src = x + (size_t)myrow * 256 + c * 32 + lg * 8;
    float4 a = *(const float4*)src;
    float4 b = *(const float4*)(src + 4);
    half8 hv;
    hv[0] = (_Float16)a.x; hv[1] = (_Float16)a.y; hv[2] = (_Float16)a.z; hv[3] = (_Float16)a.w;
    hv[4] = (_Float16)b.x; hv[5] = (_Float16)b.y; hv[6] = (_Float16)b.z; hv[7] = (_Float16)b.w;
    afr[c] = hv;
  }

  // ---- rotary angles: freq index = lg*4+j ----
  const float px = pos[(size_t)myrow * 2 + 0] * 64.0f;
  const float py = pos[(size_t)myrow * 2 + 1] * 64.0f;
  float sxj[4], cxj[4], syj[4], cyj[4];
#pragma unroll
  for (int j = 0; j < 4; ++j) {
    float invf = exp2f((float)(lg * 4 + j) * -0.8304820237218405f);  // 10000^(-fi/16)
    __sincosf(px * invf, &sxj[j], &cxj[j]);
    __sincosf(py * invf, &syj[j], &cyj[j]);
  }

  // ---- W stage for phase p (p = h*4 + kt); data index wraps past 31 ----
  auto stageP = [&](int p) {
    const int pd = p & 31;
    const int hh = pd >> 2, kt = pd & 3;
    char* dst = (char*)&rbuf[p % 3][0];
#pragma unroll
    for (int call = 0; call < 6; ++call) {
      int ob = (call * 4 + wv) * 1024;             // wave-uniform dest base (bytes)
      int o = ob + l * 16;                         // this lane's dest byte
      int c = o >> 7;                              // col 0..191
      int kb = (o & 127) ^ ((c & 7) << 4);         // logical K byte (XOR swizzle)
      int gc = ((c >> 6) << 9) + (hh << 6) + (c & 63);  // global wt row
      const char* src = (const char*)(wt + (size_t)gc * 256 + kt * 64) + kb;
      GLL(src, dst + ob);
    }
  };

  stageP(0); stageP(1);
  asm volatile("s_waitcnt vmcnt(6)" ::: "memory");   // stage(0) complete
  __builtin_amdgcn_s_barrier();

#pragma unroll 1
  for (int h = 0; h < 8; ++h) {
    f32x4 acc[12] = {};
#pragma unroll
    for (int kt = 0; kt < 4; ++kt) {               // unrolled: afr static index
      const int p = h * 4 + kt;
      stageP(p + 2);                               // 6 GLL, lands 2 phases ahead
      const char* wbp = (const char*)&rbuf[p % 3][0];
#pragma unroll
      for (int sp = 0; sp < 2; ++sp) {
        half8 af = afr[kt * 2 + sp];
        int wkb = sp * 64 + lg * 16;
#pragma unroll
        for (int cf = 0; cf < 12; ++cf) {
          int c = cf * 16 + lr;
          half8 bf = *(const half8*)(wbp + c * 128 + (wkb ^ ((c & 7) << 4)));
          // SWAPPED: A = W fragment, B = x fragment -> D[wcol][xrow]
          acc[cf] = __builtin_amdgcn_mfma_f32_16x16x32_f16(bf, af, acc[cf], 0, 0, 0);
        }
      }
      // counted: leave the newest stage (6 GLL) in flight; ensure p+1's arrived
      asm volatile("s_waitcnt vmcnt(6)" ::: "memory");
      __builtin_amdgcn_s_barrier();
    }
    // rbuf[(4h+3)%3] == rbuf[h%3] is now dead until stage(4h+6) (issued after dots)
    _Float16* dead = &rbuf[h % 3][0];   // kT: [64 d][88 rows]; vT at +5632 halfs

    // ---- epilogue (register): lane holds cols lg*4+{0..3} of row lr ----
    float sk = 0.f, sk2 = 0.f, sv = 0.f, sv2 = 0.f;
#pragma unroll
    for (int cc = 4; cc < 12; ++cc)
#pragma unroll
      for (int j = 0; j < 4; ++j) {
        float u = acc[cc][j];
        if (cc < 8) { sk += u; sk2 += u * u; } else { sv += u; sv2 += u * u; }
      }
    sk += __shfl_xor(sk, 16, 64);  sk += __shfl_xor(sk, 32, 64);
    sk2 += __shfl_xor(sk2, 16, 64); sk2 += __shfl_xor(sk2, 32, 64);
    sv += __shfl_xor(sv, 16, 64);  sv += __shfl_xor(sv, 32, 64);
    sv2 += __shfl_xor(sv2, 16, 64); sv2 += __shfl_xor(sv2, 32, 64);
    float mk = sk * 0.015625f, mv = sv * 0.015625f;
    float ik = rsqrtf(sk2 * 0.015625f - mk * mk + 1e-5f);
    float iv = rsqrtf(sv2 * 0.015625f - mv * mv + 1e-5f);

    half4 oq[4], ok[4], ov[4];
#pragma unroll
    for (int j = 0; j < 4; ++j) {
      float q0 = acc[0][j], q1 = acc[1][j], q2 = acc[2][j], q3 = acc[3][j];
      oq[0][j] = (_Float16)(q0 * cxj[j] - q1 * sxj[j]);
      oq[1][j] = (_Float16)(q1 * cxj[j] + q0 * sxj[j]);
      oq[2][j] = (_Float16)(q2 * cyj[j] - q3 * syj[j]);
      oq[3][j] = (_Float16)(q3 * cyj[j] + q2 * syj[j]);
      float k0 = (acc[4][j] - mk) * ik, k1 = (acc[5][j] - mk) * ik;
      float k2 = (acc[6][j] - mk) * ik, k3 = (acc[7][j] - mk) * ik;
      ok[0][j] = (_Float16)(k0 * cxj[j] - k1 * sxj[j]);
      ok[1][j] = (_Float16)(k1 * cxj[j] + k0 * sxj[j]);
      ok[2][j] = (_Float16)(k2 * cyj[j] - k3 * syj[j]);
      ok[3][j] = (_Float16)(k3 * cyj[j] + k2 * syj[j]);
      ov[0][j] = (_Float16)((acc[8][j]  - mv) * iv);
      ov[1][j] = (_Float16)((acc[9][j]  - mv) * iv);
      ov[2][j] = (_Float16)((acc[10][j] - mv) * iv);
      ov[3][j] = (_Float16)((acc[11][j] - mv) * iv);
    }
    // k,v -> dead buffer, transposed: kT[d][row], vT[e][row] (stride 88)
#pragma unroll
    for (int cc = 0; cc < 4; ++cc)
#pragma unroll
      for (int j = 0; j < 4; ++j) {
        int dr = (cc * 16 + lg * 4 + j) * 88 + wv * 16 + lr;
        dead[dr] = ok[cc][j];
        dead[5632 + dr] = ov[cc][j];
      }
    asm volatile("s_waitcnt lgkmcnt(0)" ::: "memory");   // LDS-only barrier (no vm drain)
    __builtin_amdgcn_s_barrier();

    // ---- dots partial: D[d][e] = sum_rows kT[d][row] vT[e][row], K=64 ----
    f32x4 dacc[4] = {};
#pragma unroll
    for (int ks = 0; ks < 2; ++ks) {
      half8 adf = *(const half8*)(dead + (wv * 16 + lr) * 88 + ks * 32 + lg * 8);
#pragma unroll
      for (int ep = 0; ep < 4; ++ep) {
        half8 bdf = *(const half8*)(dead + 5632 + (ep * 16 + lr) * 88 + ks * 32 + lg * 8);
        dacc[ep] = __builtin_amdgcn_mfma_f32_16x16x32_f16(adf, bdf, dacc[ep], 0, 0, 0);
      }
    }
    asm volatile("s_waitcnt lgkmcnt(0)" ::: "memory");   // dots reads done
    __builtin_amdgcn_s_barrier();                        // before next stage overwrites

    // q -> global (after syncs so boundary drains don't wait on these stores)
    size_t qbase = (size_t)myrow * 512 + h * 64 + lg * 4;
#pragma unroll
    for (int cc = 0; cc < 4; ++cc) *(half4*)(q16 + qbase + cc * 16) = oq[cc];
    // partial layout [e][d]: lane holds d = wv*16 + lg*4+{0..3}, e = ep*16+lr
    _Float16* pdst = part16 + ((size_t)blockIdx.x * 8 + h) * 4096;
#pragma unroll
    for (int ep = 0; ep < 4; ++ep) {
      half4 o;
#pragma unroll
      for (int j = 0; j < 4; ++j) o[j] = (_Float16)dacc[ep][j];
      *(half4*)(pdst + (ep * 16 + lr) * 64 + wv * 16 + lg * 4) = o;
    }
  }
}

// ---------------- K2: reduce 512 rowtile partials -> dots fp32 [32 bh][e*64+d] ----
__global__ void __launch_bounds__(256) k_pred(const _Float16* __restrict__ part16,
                                              float* __restrict__ dots) {
  __shared__ float red[4][512];
  const int bh = blockIdx.x >> 3, sl = blockIdx.x & 7;
  const int b = bh >> 3, h = bh & 7;
  const int t = threadIdx.x, wv = t >> 6, l = t & 63;
  float s[8] = {};
  const _Float16* base = part16 + ((size_t)(b * 128) * 8 + h) * 4096 + sl * 512 + l * 8;
#pragma unroll 4
  for (int i = 0; i < 32; ++i) {
    int rt = wv * 32 + i;
    half8 v = *(const half8*)(base + (size_t)rt * 32768);
#pragma unroll
    for (int m = 0; m < 8; ++m) s[m] += (float)v[m];
  }
#pragma unroll
  for (int m = 0; m < 8; ++m) red[wv][l * 8 + m] = s[m];
  __syncthreads();
#pragma unroll
  for (int e = t; e < 512; e += 256) {
    float r = red[0][e] + red[1][e] + red[2][e] + red[3][e];
    dots[(size_t)bh * 4096 + sl * 512 + e] = r;
  }
}

// ---------------- K2b: wdt[b][j][h*64+d] = (1/N) sum_e dotsT[e][d] wout[h*64+e][j]
// grid(32, 4): bid = b*8+h, j-quarter = blockIdx.y*64.
__global__ void __launch_bounds__(256) k_wd(const float* __restrict__ dots,
                                            const float* __restrict__ wout,
                                            _Float16* __restrict__ wdt) {
  __shared__ alignas(16) _Float16 a_lds[4096];    // [64 d][64 e] swizzled, 8 KB
  __shared__ alignas(16) _Float16 b_lds[4096];    // [64 jl][64 e] swizzled, 8 KB
  const int bid = blockIdx.x, b = bid >> 3, hh = bid & 7;
  const int j0 = blockIdx.y * 64;
  const int t = threadIdx.x, wv = t >> 6, l = t & 63, lr = l & 15, lg = l >> 4;

  // A: dots [e][d] fp32 -> a_lds [d][e] fp16 (scaled)
#pragma unroll
  for (int g = 0; g < 4; ++g) {
    int i4 = (g * 256 + t) * 4;  // 0..4095, e = i4>>6, d = i4&63
    f32x4 s = *(const f32x4*)(dots + (size_t)bid * 4096 + i4);
    int e = i4 >> 6, d0 = i4 & 63;
#pragma unroll
    for (int m = 0; m < 4; ++m) {
      int d = d0 + m;
      *(_Float16*)((char*)a_lds + d * 128 + ((e * 2) ^ ((d & 7) << 4))) =
          (_Float16)(s[m] * (1.0f / 8192.0f));
    }
  }
  // B: wout rows hh*64..+63, cols j0..+63, transposed to [jl][e] fp16
#pragma unroll
  for (int g = 0; g < 4; ++g) {
    int i4 = (g * 256 + t) * 4;  // 0..4095: e = i4>>6, jl = i4&63
    int e = i4 >> 6, jl0 = i4 & 63;
    f32x4 u = *(const f32x4*)(wout + (size_t)(hh * 64 + e) * 256 + j0 + jl0);
#pragma unroll
    for (int m = 0; m < 4; ++m) {
      int jl = jl0 + m;
      *(_Float16*)((char*)b_lds + jl * 128 + ((e * 2) ^ ((jl & 7) << 4))) = (_Float16)u[m];
    }
  }
  __syncthreads();

  f32x4 acc[4] = {};
#pragma unroll
  for (int sp = 0; sp < 2; ++sp) {
    int kb = sp * 64 + lg * 16;
    half8 bf;
    {
      int jl = wv * 16 + lr;
      bf = *(const half8*)((const char*)b_lds + jl * 128 + (kb ^ ((jl & 7) << 4)));
    }
#pragma unroll
    for (int ad = 0; ad < 4; ++ad) {
      int d = ad * 16 + lr;
      half8 af = *(const half8*)((const char*)a_lds + d * 128 + (kb ^ ((d & 7) << 4)));
      acc[ad] = __builtin_amdgcn_mfma_f32_16x16x32_f16(af, bf, acc[ad], 0, 0, 0);
    }
  }
  // D[row=d][col=j]: lane holds d = ad*16+lg*4+{0..3}, j = j0 + wv*16 + lr
#pragma unroll
  for (int ad = 0; ad < 4; ++ad) {
    int j = j0 + wv * 16 + lr;
    half4 o;
#pragma unroll
    for (int jj = 0; jj < 4; ++jj) o[jj] = (_Float16)acc[ad][jj];
    *(half4*)(wdt + (size_t)b * 131072 + (size_t)j * 512 + hh * 64 + ad * 16 + lg * 4) = o;
  }
}

// ---------------- K3: out = q16 @ wdt[b] + b_out ----------------
// 4 waves = (rh, cq): rows rh*32..+31 (2 row-frags), cols cq*128..+127 (8 frags).
// Each bf read feeds 2 MFMA (B-reuse 2): 10 reads : 16 MFMA per wave per kt.
__global__ void __launch_bounds__(256) k_out(const _Float16* __restrict__ q16,
                                             const _Float16* __restrict__ wdt,
                                             const float* __restrict__ bout,
                                             float* __restrict__ out) {
  __shared__ alignas(16) _Float16 qa[2][4096];     // [64 rows][64 K] 8 KB x2
  __shared__ alignas(16) _Float16 wtile[2][16384]; // [256 cols][64 K] 32 KB x2
  const int row0 = blockIdx.x * 64;
  const int b = row0 >> 13;
  const _Float16* wb = wdt + (size_t)b * 131072;
  const int t = threadIdx.x, wv = t >> 6, l = t & 63, lr = l & 15, lg = l >> 4;
  const int rh = wv >> 1, cq = wv & 1;

  auto stage = [&](int buf, int kt) {
#pragma unroll
    for (int call = 0; call < 2; ++call) {
      int ob = (call * 4 + wv) * 1024;
      int o = ob + l * 16;
      int r = o >> 7;
      int kb = (o & 127) ^ ((r & 7) << 4);
      const char* src = (const char*)(q16 + (size_t)(row0 + r) * 512 + kt * 64) + kb;
      GLL(src, (char*)&qa[buf][0] + ob);
    }
#pragma unroll
    for (int call = 0; call < 8; ++call) {
      int ob = (call * 4 + wv) * 1024;
      int o = ob + l * 16;
      int c = o >> 7;
      int kb = (o & 127) ^ ((c & 7) << 4);
      const char* src = (const char*)(wb + (size_t)c * 512 + kt * 64) + kb;
      GLL(src, (char*)&wtile[buf][0] + ob);
    }
  };

  f32x4 acc[8][2] = {};
  stage(0, 0);
  __syncthreads();
#pragma unroll 1
  for (int kt = 0; kt < 8; ++kt) {
    int cur = kt & 1;
    if (kt < 7) stage(cur ^ 1, kt + 1);
#pragma unroll
    for (int sp = 0; sp < 2; ++sp) {
      int kb = sp * 64 + lg * 16;
      half8 af[2];
#pragma unroll
      for (int rs = 0; rs < 2; ++rs) {
        int arow = rh * 32 + rs * 16 + lr;
        af[rs] = *(const half8*)((const char*)&qa[cur][0] + arow * 128 + (kb ^ ((arow & 7) << 4)));
      }
#pragma unroll
      for (int cf = 0; cf < 8; ++cf) {
        int c = cq * 128 + cf * 16 + lr;
        half8 bf = *(const half8*)((const char*)&wtile[cur][0] + c * 128 + (kb ^ ((c & 7) << 4)));
#pragma unroll
        for (int rs = 0; rs < 2; ++rs)
          acc[cf][rs] = __builtin_amdgcn_mfma_f32_16x16x32_f16(af[rs], bf, acc[cf][rs], 0, 0, 0);
      }
    }
    __syncthreads();
  }
#pragma unroll
  for (int cf = 0; cf < 8; ++cf) {
    int col = cq * 128 + cf * 16 + lr;
    float bo = bout[col];
#pragma unroll
    for (int rs = 0; rs < 2; ++rs)
#pragma unroll
      for (int j = 0; j < 4; ++j) {
        int grow = row0 + rh * 32 + rs * 16 + lg * 4 + j;
        out[(size_t)grow * 256 + col] = acc[cf][rs][j] + bo;
      }
  }
}

// ---------------- launch ----------------
extern "C" void kernel_launch(void* const* d_in, const int* in_sizes, int n_in,
                              void* d_out, int out_size, void* d_ws, size_t ws_size,
                              hipStream_t stream) {
  const float* x    = (const float*)d_in[0];
  const float* pos  = (const float*)d_in[1];
  const float* wqkv = (const float*)d_in[2];
  const float* wout = (const float*)d_in[3];
  const float* bout = (const float*)d_in[4];
  float* out = (float*)d_out;
  char* ws = (char*)d_ws;

  _Float16* wt16   = (_Float16*)(ws + 0);          //    786,432 B
  _Float16* q16    = (_Float16*)(ws + 786432);     // 33,554,432 B
  _Float16* part16 = (_Float16*)(ws + 34340864);   // 33,554,432 B
  float*    dots   = (float*)   (ws + 67895296);   //    524,288 B
  _Float16* wdt    = (_Float16*)(ws + 68419584);   //  1,048,576 B (end 69,468,160)

  k_cvt_w<<<1536, 256, 0, stream>>>(wqkv, wt16);
  k_qkv<<<512, 256, 0, stream>>>(x, wt16, pos, q16, part16);
  k_pred<<<256, 256, 0, stream>>>(part16, dots);
  k_wd<<<dim3(32, 4), 256, 0, stream>>>(dots, wout, wdt);
  k_out<<<512, 256, 0, stream>>>(q16, wdt, bout, out);
}

// Round 15
// 98.279 us; speedup vs baseline: 2.3871x; 1.0398x over previous
//
#include <hip/hip_runtime.h>
#include <hip/hip_fp16.h>

#define BB 4
#define NN 8192
#define DD 256
#define HH 8
#define MM 32768   // BB*NN

typedef __attribute__((ext_vector_type(8))) _Float16 half8;
typedef __attribute__((ext_vector_type(4))) _Float16 half4;
typedef __attribute__((ext_vector_type(4))) float f32x4;

#define GLL(src, dst)                                                        \
  __builtin_amdgcn_global_load_lds(                                          \
      (const __attribute__((address_space(1))) void*)(src),                  \
      (__attribute__((address_space(3))) void*)(dst), 16, 0, 0)

// ---------------- K0: W conversion ----------------
// W_qkv [256][1536] fp32 -> Wt [1536][256] fp16 (transposed)
__global__ void __launch_bounds__(256) k_cvt_w(const float* __restrict__ w,
                                               _Float16* __restrict__ wt) {
  int idx = blockIdx.x * 256 + threadIdx.x;  // 0..393215
  int k = idx / 1536, c = idx % 1536;
  wt[(size_t)c * 256 + k] = (_Float16)w[idx];
}

// ---------------- K1: kv GEMM + norm + rotary + fused dots-partial ----------------
// R7 structure with q DELETED: 64 rows, 8 heads, cols = k(64)+v(64) per head.
// W staged via 3-buffer ring (stage = 4 GLL). Invariant: at end of phase p,
// stage(p+1) must be drained -> vmcnt(4) leaves only stage(p+2) in flight.
__global__ void __launch_bounds__(256) k_qkv(const float* __restrict__ x,
                                             const _Float16* __restrict__ wt,
                                             const float* __restrict__ pos,
                                             _Float16* __restrict__ part16) {
  __shared__ alignas(16) _Float16 rbuf[3][12288];  // stage uses 16 KB; kv scratch needs 22.5 KB
  const int row0 = blockIdx.x * 64;
  const int t = threadIdx.x;
  const int wv = t >> 6, l = t & 63, lr = l & 15, lg = l >> 4;
  const int myrow = row0 + wv * 16 + lr;

  // ---- x fragments: coalesced global loads, fp32 -> fp16, registers ----
  half8 afr[8];
#pragma unroll
  for (int c = 0; c < 8; ++c) {      // c = kt*2 + sp
    const float* src = x + (size_t)myrow * 256 + c * 32 + lg * 8;
    float4 a = *(const float4*)src;
    float4 b = *(const float4*)(src + 4);
    half8 hv;
    hv[0] = (_Float16)a.x; hv[1] = (_Float16)a.y; hv[2] = (_Float16)a.z; hv[3] = (_Float16)a.w;
    hv[4] = (_Float16)b.x; hv[5] = (_Float16)b.y; hv[6] = (_Float16)b.z; hv[7] = (_Float16)b.w;
    afr[c] = hv;
  }

  // ---- rotary angles (for k): freq index = lg*4+j ----
  const float px = pos[(size_t)myrow * 2 + 0] * 64.0f;
  const float py = pos[(size_t)myrow * 2 + 1] * 64.0f;
  float sxj[4], cxj[4], syj[4], cyj[4];
#pragma unroll
  for (int j = 0; j < 4; ++j) {
    float invf = exp2f((float)(lg * 4 + j) * -0.8304820237218405f);  // 10000^(-fi/16)
    __sincosf(px * invf, &sxj[j], &cxj[j]);
    __sincosf(py * invf, &syj[j], &cyj[j]);
  }

  // ---- W stage for phase p (p = h*4 + kt): k,v sections only (128 cols) ----
  auto stageP = [&](int p) {
    const int pd = p & 31;
    const int hh = pd >> 2, kt = pd & 3;
    char* dst = (char*)&rbuf[p % 3][0];
#pragma unroll
    for (int call = 0; call < 4; ++call) {
      int ob = (call * 4 + wv) * 1024;             // wave-uniform dest base (bytes)
      int o = ob + l * 16;                         // this lane's dest byte
      int c = o >> 7;                              // col 0..127 (0-63=k, 64-127=v)
      int kb = (o & 127) ^ ((c & 7) << 4);         // logical K byte (XOR swizzle)
      int gc = ((c >> 6) + 1) * 512 + (hh << 6) + (c & 63);  // wt row (k/v sections)
      const char* src = (const char*)(wt + (size_t)gc * 256 + kt * 64) + kb;
      GLL(src, dst + ob);
    }
  };

  stageP(0); stageP(1);
  asm volatile("s_waitcnt vmcnt(4)" ::: "memory");   // stage(0) complete
  __builtin_amdgcn_s_barrier();

#pragma unroll 1
  for (int h = 0; h < 8; ++h) {
    f32x4 acc[8] = {};                 // 0-3 = k, 4-7 = v
#pragma unroll
    for (int kt = 0; kt < 4; ++kt) {   // unrolled: afr static index
      const int p = h * 4 + kt;
      stageP(p + 2);                   // 4 GLL, lands 2 phases ahead
      const char* wbp = (const char*)&rbuf[p % 3][0];
#pragma unroll
      for (int sp = 0; sp < 2; ++sp) {
        half8 af = afr[kt * 2 + sp];
        int wkb = sp * 64 + lg * 16;
#pragma unroll
        for (int cf = 0; cf < 8; ++cf) {
          int c = cf * 16 + lr;
          half8 bf = *(const half8*)(wbp + c * 128 + (wkb ^ ((c & 7) << 4)));
          // SWAPPED: A = W fragment, B = x fragment -> D[wcol][xrow]
          acc[cf] = __builtin_amdgcn_mfma_f32_16x16x32_f16(bf, af, acc[cf], 0, 0, 0);
        }
      }
      // counted: leave only stage(p+2) [4 ops] in flight -> stage(p+1) drained
      asm volatile("s_waitcnt vmcnt(4)" ::: "memory");
      __builtin_amdgcn_s_barrier();
    }
    // rbuf[(4h+3)%3] == rbuf[h%3] is dead until stage(4h+6)
    _Float16* dead = &rbuf[h % 3][0];   // kT: [64 d][88 rows]; vT at +5632 halfs

    // ---- norms (in-wave): k = acc[0..3], v = acc[4..7] ----
    float sk = 0.f, sk2 = 0.f, sv = 0.f, sv2 = 0.f;
#pragma unroll
    for (int cc = 0; cc < 8; ++cc)
#pragma unroll
      for (int j = 0; j < 4; ++j) {
        float u = acc[cc][j];
        if (cc < 4) { sk += u; sk2 += u * u; } else { sv += u; sv2 += u * u; }
      }
    sk += __shfl_xor(sk, 16, 64);  sk += __shfl_xor(sk, 32, 64);
    sk2 += __shfl_xor(sk2, 16, 64); sk2 += __shfl_xor(sk2, 32, 64);
    sv += __shfl_xor(sv, 16, 64);  sv += __shfl_xor(sv, 32, 64);
    sv2 += __shfl_xor(sv2, 16, 64); sv2 += __shfl_xor(sv2, 32, 64);
    float mk = sk * 0.015625f, mv = sv * 0.015625f;
    float ik = rsqrtf(sk2 * 0.015625f - mk * mk + 1e-5f);
    float iv = rsqrtf(sv2 * 0.015625f - mv * mv + 1e-5f);

    half4 ok[4], ov[4];
#pragma unroll
    for (int j = 0; j < 4; ++j) {
      float k0 = (acc[0][j] - mk) * ik, k1 = (acc[1][j] - mk) * ik;
      float k2 = (acc[2][j] - mk) * ik, k3 = (acc[3][j] - mk) * ik;
      ok[0][j] = (_Float16)(k0 * cxj[j] - k1 * sxj[j]);
      ok[1][j] = (_Float16)(k1 * cxj[j] + k0 * sxj[j]);
      ok[2][j] = (_Float16)(k2 * cyj[j] - k3 * syj[j]);
      ok[3][j] = (_Float16)(k3 * cyj[j] + k2 * syj[j]);
      ov[0][j] = (_Float16)((acc[4][j] - mv) * iv);
      ov[1][j] = (_Float16)((acc[5][j] - mv) * iv);
      ov[2][j] = (_Float16)((acc[6][j] - mv) * iv);
      ov[3][j] = (_Float16)((acc[7][j] - mv) * iv);
    }
    // k,v -> dead buffer, transposed: kT[d][row], vT[e][row] (stride 88)
#pragma unroll
    for (int cc = 0; cc < 4; ++cc)
#pragma unroll
      for (int j = 0; j < 4; ++j) {
        int dr = (cc * 16 + lg * 4 + j) * 88 + wv * 16 + lr;
        dead[dr] = ok[cc][j];
        dead[5632 + dr] = ov[cc][j];
      }
    asm volatile("s_waitcnt lgkmcnt(0)" ::: "memory");   // LDS-only barrier (no vm drain)
    __builtin_amdgcn_s_barrier();

    // ---- dots partial: D[d][e] = sum_rows kT[d][row] vT[e][row], K=64 ----
    f32x4 dacc[4] = {};
#pragma unroll
    for (int ks = 0; ks < 2; ++ks) {
      half8 adf = *(const half8*)(dead + (wv * 16 + lr) * 88 + ks * 32 + lg * 8);
#pragma unroll
      for (int ep = 0; ep < 4; ++ep) {
        half8 bdf = *(const half8*)(dead + 5632 + (ep * 16 + lr) * 88 + ks * 32 + lg * 8);
        dacc[ep] = __builtin_amdgcn_mfma_f32_16x16x32_f16(adf, bdf, dacc[ep], 0, 0, 0);
      }
    }
    asm volatile("s_waitcnt lgkmcnt(0)" ::: "memory");   // dots reads done
    __builtin_amdgcn_s_barrier();                        // before next stage overwrites

    // partial layout [e][d]: lane holds d = wv*16 + lg*4+{0..3}, e = ep*16+lr
    _Float16* pdst = part16 + ((size_t)blockIdx.x * 8 + h) * 4096;
#pragma unroll
    for (int ep = 0; ep < 4; ++ep) {
      half4 o;
#pragma unroll
      for (int j = 0; j < 4; ++j) o[j] = (_Float16)dacc[ep][j];
      *(half4*)(pdst + (ep * 16 + lr) * 64 + wv * 16 + lg * 4) = o;
    }
  }
}

// ---------------- K2: reduce 512 rowtile partials -> dots fp32 [32 bh][e*64+d] ----
__global__ void __launch_bounds__(256) k_pred(const _Float16* __restrict__ part16,
                                              float* __restrict__ dots) {
  __shared__ float red[4][512];
  const int bh = blockIdx.x >> 3, sl = blockIdx.x & 7;
  const int b = bh >> 3, h = bh & 7;
  const int t = threadIdx.x, wv = t >> 6, l = t & 63;
  float s[8] = {};
  const _Float16* base = part16 + ((size_t)(b * 128) * 8 + h) * 4096 + sl * 512 + l * 8;
#pragma unroll 4
  for (int i = 0; i < 32; ++i) {
    int rt = wv * 32 + i;
    half8 v = *(const half8*)(base + (size_t)rt * 32768);
#pragma unroll
    for (int m = 0; m < 8; ++m) s[m] += (float)v[m];
  }
#pragma unroll
  for (int m = 0; m < 8; ++m) red[wv][l * 8 + m] = s[m];
  __syncthreads();
#pragma unroll
  for (int e = t; e < 512; e += 256) {
    float r = red[0][e] + red[1][e] + red[2][e] + red[3][e];
    dots[(size_t)bh * 4096 + sl * 512 + e] = r;
  }
}

// ---------------- K2b: wdt[b][j][h*64+d] = (1/N) sum_e dotsT[e][d] wout[h*64+e][j]
// grid(32, 4): bid = b*8+h, j-quarter = blockIdx.y*64.
__global__ void __launch_bounds__(256) k_wd(const float* __restrict__ dots,
                                            const float* __restrict__ wout,
                                            _Float16* __restrict__ wdt) {
  __shared__ alignas(16) _Float16 a_lds[4096];    // [64 d][64 e] swizzled, 8 KB
  __shared__ alignas(16) _Float16 b_lds[4096];    // [64 jl][64 e] swizzled, 8 KB
  const int bid = blockIdx.x, b = bid >> 3, hh = bid & 7;
  const int j0 = blockIdx.y * 64;
  const int t = threadIdx.x, wv = t >> 6, l = t & 63, lr = l & 15, lg = l >> 4;

  // A: dots [e][d] fp32 -> a_lds [d][e] fp16 (scaled)
#pragma unroll
  for (int g = 0; g < 4; ++g) {
    int i4 = (g * 256 + t) * 4;  // 0..4095, e = i4>>6, d = i4&63
    f32x4 s = *(const f32x4*)(dots + (size_t)bid * 4096 + i4);
    int e = i4 >> 6, d0 = i4 & 63;
#pragma unroll
    for (int m = 0; m < 4; ++m) {
      int d = d0 + m;
      *(_Float16*)((char*)a_lds + d * 128 + ((e * 2) ^ ((d & 7) << 4))) =
          (_Float16)(s[m] * (1.0f / 8192.0f));
    }
  }
  // B: wout rows hh*64..+63, cols j0..+63, transposed to [jl][e] fp16
#pragma unroll
  for (int g = 0; g < 4; ++g) {
    int i4 = (g * 256 + t) * 4;  // 0..4095: e = i4>>6, jl = i4&63
    int e = i4 >> 6, jl0 = i4 & 63;
    f32x4 u = *(const f32x4*)(wout + (size_t)(hh * 64 + e) * 256 + j0 + jl0);
#pragma unroll
    for (int m = 0; m < 4; ++m) {
      int jl = jl0 + m;
      *(_Float16*)((char*)b_lds + jl * 128 + ((e * 2) ^ ((jl & 7) << 4))) = (_Float16)u[m];
    }
  }
  __syncthreads();

  f32x4 acc[4] = {};
#pragma unroll
  for (int sp = 0; sp < 2; ++sp) {
    int kb = sp * 64 + lg * 16;
    half8 bf;
    {
      int jl = wv * 16 + lr;
      bf = *(const half8*)((const char*)b_lds + jl * 128 + (kb ^ ((jl & 7) << 4)));
    }
#pragma unroll
    for (int ad = 0; ad < 4; ++ad) {
      int d = ad * 16 + lr;
      half8 af = *(const half8*)((const char*)a_lds + d * 128 + (kb ^ ((d & 7) << 4)));
      acc[ad] = __builtin_amdgcn_mfma_f32_16x16x32_f16(af, bf, acc[ad], 0, 0, 0);
    }
  }
  // D[row=d][col=j]: lane holds d = ad*16+lg*4+{0..3}, j = j0 + wv*16 + lr
#pragma unroll
  for (int ad = 0; ad < 4; ++ad) {
    int j = j0 + wv * 16 + lr;
    half4 o;
#pragma unroll
    for (int jj = 0; jj < 4; ++jj) o[jj] = (_Float16)acc[ad][jj];
    *(half4*)(wdt + (size_t)b * 131072 + (size_t)j * 512 + hh * 64 + ad * 16 + lg * 4) = o;
  }
}

// ---------------- K3: out = rope(x@Wq) @ wdt[b] + b_out  (q recomputed in-kernel) ----
// Per head h: 4 q-sub-phases (Wq 3-ring, 2 GLL/stage, swapped MFMA) -> rope ->
// q-tile to LDS (swizzled) -> out-MFMA (R13 map, B-reuse 2). wtile staged per head.
// Invariant: end-of-phase vmcnt(2) leaves only stage(p+2) -> stage(p+1) drained.
__global__ void __launch_bounds__(256) k_out(const float* __restrict__ x,
                                             const _Float16* __restrict__ wt,
                                             const float* __restrict__ pos,
                                             const _Float16* __restrict__ wdt,
                                             const float* __restrict__ bout,
                                             float* __restrict__ out) {
  __shared__ alignas(16) _Float16 wqr[3][4096];    // [64 qcols][64 K] swizzled, 8 KB x3
  __shared__ alignas(16) _Float16 qtile[4096];     // [64 rows][64 d] swizzled, 8 KB
  __shared__ alignas(16) _Float16 wtile[16384];    // [256 j][64 d] swizzled, 32 KB
  const int row0 = blockIdx.x * 64;
  const int b = row0 >> 13;
  const int t = threadIdx.x, wv = t >> 6, l = t & 63, lr = l & 15, lg = l >> 4;
  const int rh = wv >> 1, cq = wv & 1;
  const int myrow = row0 + wv * 16 + lr;

  // ---- x fragments in registers (same as k_qkv) ----
  half8 afr[8];
#pragma unroll
  for (int c = 0; c < 8; ++c) {
    const float* src = x + (size_t)myrow * 256 + c * 32 + lg * 8;
    float4 a = *(const float4*)src;
    float4 bb = *(const float4*)(src + 4);
    half8 hv;
    hv[0] = (_Float16)a.x; hv[1] = (_Float16)a.y; hv[2] = (_Float16)a.z; hv[3] = (_Float16)a.w;
    hv[4] = (_Float16)bb.x; hv[5] = (_Float16)bb.y; hv[6] = (_Float16)bb.z; hv[7] = (_Float16)bb.w;
    afr[c] = hv;
  }

  // ---- rotary angles (for q): freq index = lg*4+j ----
  const float px = pos[(size_t)myrow * 2 + 0] * 64.0f;
  const float py = pos[(size_t)myrow * 2 + 1] * 64.0f;
  float sxj[4], cxj[4], syj[4], cyj[4];
#pragma unroll
  for (int j = 0; j < 4; ++j) {
    float invf = exp2f((float)(lg * 4 + j) * -0.8304820237218405f);
    __sincosf(px * invf, &sxj[j], &cxj[j]);
    __sincosf(py * invf, &syj[j], &cyj[j]);
  }

  // ---- wtile stage for head hh: [256 j][64 d] from wdt[b][j][hh*64+d] (8 GLL) ----
  auto stageWT = [&](int hh) {
#pragma unroll
    for (int call = 0; call < 8; ++call) {
      int ob = (call * 4 + wv) * 1024;
      int o = ob + l * 16;
      int c = o >> 7;                              // j 0..255
      int kb = (o & 127) ^ ((c & 7) << 4);
      const char* src = (const char*)(wdt + (size_t)b * 131072 + (size_t)c * 512 + hh * 64) + kb;
      GLL(src, (char*)wtile + ob);
    }
  };
  // ---- Wq panel stage for phase p = h*4 + kt (2 GLL) ----
  auto stageWQ = [&](int p) {
    const int pd = p & 31;
    const int hq = pd >> 2, ktq = pd & 3;
    char* dst = (char*)&wqr[p % 3][0];
#pragma unroll
    for (int call = 0; call < 2; ++call) {
      int ob = (call * 4 + wv) * 1024;
      int o = ob + l * 16;
      int c = o >> 7;                              // q col 0..63
      int kb = (o & 127) ^ ((c & 7) << 4);
      int gc = (hq << 6) + (c & 63);               // wt row (q section = rows 0..511)
      const char* src = (const char*)(wt + (size_t)gc * 256 + ktq * 64) + kb;
      GLL(src, dst + ob);
    }
  };

  stageWT(0); stageWQ(0); stageWQ(1);
  asm volatile("s_waitcnt vmcnt(2)" ::: "memory");   // wtile(0)+wq(0) complete
  __builtin_amdgcn_s_barrier();

  f32x4 aco[8][2] = {};   // out accumulator, persists across heads
#pragma unroll 1
  for (int h = 0; h < 8; ++h) {
    // ---- q GEMM: 4 sub-phases, K=256 ----
    f32x4 aq[4] = {};
#pragma unroll
    for (int sub = 0; sub < 4; ++sub) {
      const int p = h * 4 + sub;
      stageWQ(p + 2);
      const char* wbp = (const char*)&wqr[p % 3][0];
#pragma unroll
      for (int sp = 0; sp < 2; ++sp) {
        half8 af = afr[sub * 2 + sp];
        int wkb = sp * 64 + lg * 16;
#pragma unroll
        for (int cf = 0; cf < 4; ++cf) {
          int c = cf * 16 + lr;
          half8 bf = *(const half8*)(wbp + c * 128 + (wkb ^ ((c & 7) << 4)));
          aq[cf] = __builtin_amdgcn_mfma_f32_16x16x32_f16(bf, af, aq[cf], 0, 0, 0);
        }
      }
      // counted: leave only stage(p+2) [2 ops] -> stage(p+1) + wtile drained
      asm volatile("s_waitcnt vmcnt(2)" ::: "memory");
      __builtin_amdgcn_s_barrier();
    }
    // ---- rope + q-tile write (lane holds q-cols cf*16+lg*4+j of row lr) ----
    {
      half4 oq[4];
#pragma unroll
      for (int j = 0; j < 4; ++j) {
        float q0 = aq[0][j], q1 = aq[1][j], q2 = aq[2][j], q3 = aq[3][j];
        oq[0][j] = (_Float16)(q0 * cxj[j] - q1 * sxj[j]);
        oq[1][j] = (_Float16)(q1 * cxj[j] + q0 * sxj[j]);
        oq[2][j] = (_Float16)(q2 * cyj[j] - q3 * syj[j]);
        oq[3][j] = (_Float16)(q3 * cyj[j] + q2 * syj[j]);
      }
      int row = wv * 16 + lr;
#pragma unroll
      for (int cc = 0; cc < 4; ++cc)
        *(half4*)((char*)qtile + row * 128 + ((cc * 32 + lg * 8) ^ ((row & 7) << 4))) = oq[cc];
    }
    asm volatile("s_waitcnt lgkmcnt(0)" ::: "memory");
    __builtin_amdgcn_s_barrier();

    // ---- out-MFMA: K=64 (head h). waves (rh,cq), B-reuse 2 (R13-verified map) ----
#pragma unroll
    for (int sp = 0; sp < 2; ++sp) {
      int kb = sp * 64 + lg * 16;
      half8 af2[2];
#pragma unroll
      for (int rs = 0; rs < 2; ++rs) {
        int arow = rh * 32 + rs * 16 + lr;
        af2[rs] = *(const half8*)((const char*)qtile + arow * 128 + (kb ^ ((arow & 7) << 4)));
      }
#pragma unroll
      for (int cf = 0; cf < 8; ++cf) {
        int c = cq * 128 + cf * 16 + lr;
        half8 bf = *(const half8*)((const char*)wtile + c * 128 + (kb ^ ((c & 7) << 4)));
#pragma unroll
        for (int rs = 0; rs < 2; ++rs)
          aco[cf][rs] = __builtin_amdgcn_mfma_f32_16x16x32_f16(af2[rs], bf, aco[cf][rs], 0, 0, 0);
      }
    }
    asm volatile("s_waitcnt lgkmcnt(0)" ::: "memory");   // qtile/wtile reads done
    __builtin_amdgcn_s_barrier();
    if (h < 7) stageWT(h + 1);                           // restage after reads complete
  }
  // ---- store (R13 exact) ----
#pragma unroll
  for (int cf = 0; cf < 8; ++cf) {
    int col = cq * 128 + cf * 16 + lr;
    float bo = bout[col];
#pragma unroll
    for (int rs = 0; rs < 2; ++rs)
#pragma unroll
      for (int j = 0; j < 4; ++j) {
        int grow = row0 + rh * 32 + rs * 16 + lg * 4 + j;
        out[(size_t)grow * 256 + col] = aco[cf][rs][j] + bo;
      }
  }
}

// ---------------- launch ----------------
extern "C" void kernel_launch(void* const* d_in, const int* in_sizes, int n_in,
                              void* d_out, int out_size, void* d_ws, size_t ws_size,
                              hipStream_t stream) {
  const float* x    = (const float*)d_in[0];
  const float* pos  = (const float*)d_in[1];
  const float* wqkv = (const float*)d_in[2];
  const float* wout = (const float*)d_in[3];
  const float* bout = (const float*)d_in[4];
  float* out = (float*)d_out;
  char* ws = (char*)d_ws;

  _Float16* wt16   = (_Float16*)(ws + 0);          //    786,432 B
  _Float16* part16 = (_Float16*)(ws + 786432);     // 33,554,432 B
  float*    dots   = (float*)   (ws + 34340864);   //    524,288 B
  _Float16* wdt    = (_Float16*)(ws + 34865152);   //  1,048,576 B (end 35,913,728)

  k_cvt_w<<<1536, 256, 0, stream>>>(wqkv, wt16);
  k_qkv<<<512, 256, 0, stream>>>(x, wt16, pos, part16);
  k_pred<<<256, 256, 0, stream>>>(part16, dots);
  k_wd<<<dim3(32, 4), 256, 0, stream>>>(dots, wout, wdt);
  k_out<<<512, 256, 0, stream>>>(x, wt16, pos, wdt, bout, out);
}